// Round 10
// baseline (172.108 us; speedup 1.0000x reference)
//
#include <hip/hip_runtime.h>
#include <hip/hip_bf16.h>

#define NB 32
#define NS 512
#define NC 256
#define NKSTEP 24      // K=768 im2col / 32
#define TROWS 30       // useful output rows per conv block
#define NT 18          // tiles per batch: 18*30 = 540 >= 512
#define HROWS 32       // h rows per block (s0-1 .. s0+30)
#define XROWS 34       // x rows staged  (s0-2 .. s0+31)
#define CONV_BLOCKS (NB * NT)   // 576
#define FPW 8          // frames per wave in gather

typedef __attribute__((ext_vector_type(8))) short short8;
typedef __attribute__((ext_vector_type(4))) float f32x4;

__device__ __forceinline__ unsigned pack2(float a, float b) {
    __hip_bfloat16 ha = __float2bfloat16(a), hb = __float2bfloat16(b);
    return ((unsigned)(*(unsigned short*)&hb) << 16) | (unsigned)(*(unsigned short*)&ha);
}

// blocks 0..511: repack weights w[f][d][k] -> Bp[kstep][f][kgroup][8] bf16
// blocks 512..543: per-batch cumsum of rint(target) + scatter frame->row map
__global__ __launch_bounds__(256) void prep_and_scan(
    const float* __restrict__ w1, const float* __restrict__ w2,
    unsigned short* __restrict__ Bp1, unsigned short* __restrict__ Bp2,
    const float* __restrict__ target, int* __restrict__ idx, int L)
{
    __shared__ int bufa[512], bufb[512];
    const int t = threadIdx.x;

    if (blockIdx.x < 512) {
        const bool second = blockIdx.x >= 256;
        const int f = blockIdx.x & 255;
        const float* w = second ? w2 : w1;
        unsigned short* Bp = second ? Bp2 : Bp1;
        const float* wf = w + (size_t)f * 768 + t * 3;
        const float v[3] = {wf[0], wf[1], wf[2]};
#pragma unroll
        for (int shift = 0; shift < 3; ++shift) {
            const int k = shift * 256 + t;
            const int o = f * 32 + (k >> 5) * 8192 + (k & 31);
            __hip_bfloat16 h = __float2bfloat16(v[shift]);
            Bp[o] = *(unsigned short*)&h;
        }
        return;
    }

    const int b = blockIdx.x - 512;
    const float* tb = target + (size_t)b * NS;
    const int d0 = (int)rintf(tb[t]);
    const int d1 = (int)rintf(tb[t + 256]);
    bufa[t] = d0; bufa[t + 256] = d1;
    __syncthreads();
    int* src = bufa;
    int* dst = bufb;
    for (int off = 1; off < 512; off <<= 1) {
        for (int i = t; i < 512; i += 256) {
            int v = src[i];
            if (i >= off) v += src[i - off];
            dst[i] = v;
        }
        __syncthreads();
        int* tmp = src; src = dst; dst = tmp;
    }
    const int e0 = src[t], e1 = src[t + 256], total = src[511];
    int* ib = idx + (size_t)b * L;
    const int hi0 = e0 < L ? e0 : L;
    const int hi1 = e1 < L ? e1 : L;
    for (int k = e0 - d0; k < hi0; ++k) ib[k] = t;
    for (int k = e1 - d1; k < hi1; ++k) ib[k] = t + 256;
    for (int k = total + t; k < L; k += 256) ib[k] = -1;
}

// Fully-fused duration predictor: conv1+LN+ReLU -> LDS (hs aliases xs),
// conv2+LN+ReLU -> dot(lin_w)+ReLU -> pred. 576 blocks, all co-resident.
__global__ __launch_bounds__(256, 4) void conv_fused(
    const float* __restrict__ x,
    const uint4* __restrict__ Bp1, const uint4* __restrict__ Bp2,
    const float* __restrict__ bias1, const float* __restrict__ g1, const float* __restrict__ be1,
    const float* __restrict__ bias2, const float* __restrict__ g2, const float* __restrict__ be2,
    const float* __restrict__ linw, const float* __restrict__ linb,
    float* __restrict__ pred)
{
    __shared__ __align__(16) uint4 xs[XROWS * 32];   // 34 x 256 bf16, swizzled (17408B)
    __shared__ float red[HROWS][4][2];
    __shared__ float dotb[HROWS][4];
    unsigned short* hs = (unsigned short*)xs;        // h-tile alias (32 x 256 bf16)

    const int tid = threadIdx.x;
    const int b  = blockIdx.x / NT;
    const int t  = blockIdx.x - b * NT;
    const int s0 = t * TROWS;

    // stage x rows s0-2 .. s0+31 as bf16, swizzled (slot ^= (row&7)<<2)
    {
        const int slot = tid & 31;
        for (int r = tid >> 5; r < XROWS; r += 8) {
            const int s = s0 - 2 + r;
            uint4 v = {0u, 0u, 0u, 0u};
            if (s >= 0 && s < NS) {
                const float* src = x + ((size_t)(b * NS + s)) * NC + slot * 8;
                const float4 lo = *(const float4*)src;
                const float4 hi = *(const float4*)(src + 4);
                v.x = pack2(lo.x, lo.y); v.y = pack2(lo.z, lo.w);
                v.z = pack2(hi.x, hi.y); v.w = pack2(hi.z, hi.w);
            }
            xs[r * 32 + (slot ^ ((r & 7) << 2))] = v;
        }
    }
    __syncthreads();

    const int lane = tid & 63;
    const int w    = tid >> 6;
    const int n0   = w << 6;
    const int l15  = lane & 15;
    const int lg   = lane >> 4;

    auto ldax = [&](int ks, int mi) -> short8 {
        const int row = mi * 16 + l15 + (ks >> 3);
        int slot = ((ks & 7) << 2) + lg;
        slot ^= (row & 7) << 2;
        return *(const short8*)&xs[row * 32 + slot];
    };
    auto ldah = [&](int ks, int mi) -> short8 {
        const int row = mi * 16 + l15 + (ks >> 3);
        int slot = ((ks & 7) << 2) + lg;
        slot ^= (row & 7) << 2;
        return *(const short8*)&hs[row * 256 + slot * 8];
    };

    const uint4* bb1 = Bp1 + (size_t)(n0 + l15) * 4 + lg;
    const uint4* bb2 = Bp2 + (size_t)(n0 + l15) * 4 + lg;

    f32x4 acc[2][4];
    short8 areg[2][2], breg[2][4];

    // ======== conv1: h rows 0..31 (seq s0-1 .. s0+30) ========
#pragma unroll
    for (int mi = 0; mi < 2; ++mi)
#pragma unroll
        for (int ni = 0; ni < 4; ++ni) acc[mi][ni] = (f32x4){0.f, 0.f, 0.f, 0.f};
#pragma unroll
    for (int q = 0; q < 2; ++q) {
#pragma unroll
        for (int ni = 0; ni < 4; ++ni) breg[q][ni] = *(const short8*)(const void*)(bb1 + q * 1024 + ni * 64);
#pragma unroll
        for (int mi = 0; mi < 2; ++mi) areg[q][mi] = ldax(q, mi);
    }
#pragma unroll
    for (int p = 0; p < NKSTEP; ++p) {
        const int rs = p & 1;
#pragma unroll
        for (int mi = 0; mi < 2; ++mi)
#pragma unroll
            for (int ni = 0; ni < 4; ++ni)
                acc[mi][ni] = __builtin_amdgcn_mfma_f32_16x16x32_bf16(
                    areg[rs][mi], breg[rs][ni], acc[mi][ni], 0, 0, 0);
        if (p + 2 < NKSTEP) {
#pragma unroll
            for (int ni = 0; ni < 4; ++ni) breg[rs][ni] = *(const short8*)(const void*)(bb1 + (p + 2) * 1024 + ni * 64);
#pragma unroll
            for (int mi = 0; mi < 2; ++mi) areg[rs][mi] = ldax(p + 2, mi);
        }
    }

    // LN1 stats
    {
        float bv[4];
#pragma unroll
        for (int ni = 0; ni < 4; ++ni) bv[ni] = bias1[n0 + ni * 16 + l15];
#pragma unroll
        for (int mi = 0; mi < 2; ++mi) {
            float s[4] = {0, 0, 0, 0}, q[4] = {0, 0, 0, 0};
#pragma unroll
            for (int ni = 0; ni < 4; ++ni)
#pragma unroll
                for (int i = 0; i < 4; ++i) {
                    const float v = (acc[mi][ni][i] += bv[ni]);
                    s[i] += v; q[i] += v * v;
                }
#pragma unroll
            for (int i = 0; i < 4; ++i)
#pragma unroll
                for (int m = 1; m < 16; m <<= 1) {
                    s[i] += __shfl_xor(s[i], m, 64);
                    q[i] += __shfl_xor(q[i], m, 64);
                }
            if (l15 == 0) {
#pragma unroll
                for (int i = 0; i < 4; ++i) {
                    red[mi * 16 + lg * 4 + i][w][0] = s[i];
                    red[mi * 16 + lg * 4 + i][w][1] = q[i];
                }
            }
        }
    }
    __syncthreads();   // all xs reads done -> hs may overwrite xs

    // LN1 apply + ReLU + zero seq-pad rows -> hs (swizzled bf16, aliases xs)
    {
        float gv[4], bt[4];
#pragma unroll
        for (int ni = 0; ni < 4; ++ni) { gv[ni] = g1[n0 + ni * 16 + l15]; bt[ni] = be1[n0 + ni * 16 + l15]; }
#pragma unroll
        for (int mi = 0; mi < 2; ++mi)
#pragma unroll
            for (int i = 0; i < 4; ++i) {
                const int row = mi * 16 + lg * 4 + i;
                const int sh  = s0 - 1 + row;
                const bool ok = (sh >= 0) && (sh < NS);
                float sum = 0.f, sq = 0.f;
#pragma unroll
                for (int ww = 0; ww < 4; ++ww) { sum += red[row][ww][0]; sq += red[row][ww][1]; }
                const float mu = sum * (1.f / 256.f);
                const float rs = rsqrtf(sq * (1.f / 256.f) - mu * mu + 1e-5f);
#pragma unroll
                for (int ni = 0; ni < 4; ++ni) {
                    const int col = n0 + ni * 16 + l15;
                    float y = fmaxf(0.f, (acc[mi][ni][i] - mu) * rs * gv[ni] + bt[ni]);
                    if (!ok) y = 0.f;
                    __hip_bfloat16 hv = __float2bfloat16(y);
                    const int slot = (col >> 3) ^ ((row & 7) << 2);
                    hs[row * 256 + slot * 8 + (col & 7)] = *(unsigned short*)&hv;
                }
            }
    }
    __syncthreads();

    // ======== conv2: out rows 0..31, rows >= TROWS discarded ========
#pragma unroll
    for (int mi = 0; mi < 2; ++mi)
#pragma unroll
        for (int ni = 0; ni < 4; ++ni) acc[mi][ni] = (f32x4){0.f, 0.f, 0.f, 0.f};
#pragma unroll
    for (int q = 0; q < 2; ++q) {
#pragma unroll
        for (int ni = 0; ni < 4; ++ni) breg[q][ni] = *(const short8*)(const void*)(bb2 + q * 1024 + ni * 64);
#pragma unroll
        for (int mi = 0; mi < 2; ++mi) areg[q][mi] = ldah(q, mi);
    }
#pragma unroll
    for (int p = 0; p < NKSTEP; ++p) {
        const int rs = p & 1;
#pragma unroll
        for (int mi = 0; mi < 2; ++mi)
#pragma unroll
            for (int ni = 0; ni < 4; ++ni)
                acc[mi][ni] = __builtin_amdgcn_mfma_f32_16x16x32_bf16(
                    areg[rs][mi], breg[rs][ni], acc[mi][ni], 0, 0, 0);
        if (p + 2 < NKSTEP) {
#pragma unroll
            for (int ni = 0; ni < 4; ++ni) breg[rs][ni] = *(const short8*)(const void*)(bb2 + (p + 2) * 1024 + ni * 64);
#pragma unroll
            for (int mi = 0; mi < 2; ++mi) areg[rs][mi] = ldah(p + 2, mi);
        }
    }

    // LN2 stats
    {
        float bv[4];
#pragma unroll
        for (int ni = 0; ni < 4; ++ni) bv[ni] = bias2[n0 + ni * 16 + l15];
#pragma unroll
        for (int mi = 0; mi < 2; ++mi) {
            float s[4] = {0, 0, 0, 0}, q[4] = {0, 0, 0, 0};
#pragma unroll
            for (int ni = 0; ni < 4; ++ni)
#pragma unroll
                for (int i = 0; i < 4; ++i) {
                    const float v = (acc[mi][ni][i] += bv[ni]);
                    s[i] += v; q[i] += v * v;
                }
#pragma unroll
            for (int i = 0; i < 4; ++i)
#pragma unroll
                for (int m = 1; m < 16; m <<= 1) {
                    s[i] += __shfl_xor(s[i], m, 64);
                    q[i] += __shfl_xor(q[i], m, 64);
                }
            if (l15 == 0) {
#pragma unroll
                for (int i = 0; i < 4; ++i) {
                    red[mi * 16 + lg * 4 + i][w][0] = s[i];
                    red[mi * 16 + lg * 4 + i][w][1] = q[i];
                }
            }
        }
    }
    __syncthreads();

    // LN2 apply + ReLU + dot(lin_w) partials
    {
        float gv[4], bt[4], lwv[4];
#pragma unroll
        for (int ni = 0; ni < 4; ++ni) {
            const int col = n0 + ni * 16 + l15;
            gv[ni] = g2[col]; bt[ni] = be2[col]; lwv[ni] = linw[col];
        }
#pragma unroll
        for (int mi = 0; mi < 2; ++mi)
#pragma unroll
            for (int i = 0; i < 4; ++i) {
                const int row = mi * 16 + lg * 4 + i;
                float sum = 0.f, sq = 0.f;
#pragma unroll
                for (int ww = 0; ww < 4; ++ww) { sum += red[row][ww][0]; sq += red[row][ww][1]; }
                const float mu = sum * (1.f / 256.f);
                const float rs = rsqrtf(sq * (1.f / 256.f) - mu * mu + 1e-5f);
                float p = 0.f;
#pragma unroll
                for (int ni = 0; ni < 4; ++ni)
                    p += fmaxf(0.f, (acc[mi][ni][i] - mu) * rs * gv[ni] + bt[ni]) * lwv[ni];
#pragma unroll
                for (int m = 1; m < 16; m <<= 1) p += __shfl_xor(p, m, 64);
                if (l15 == 0) dotb[row][w] = p;
            }
    }
    __syncthreads();

    if (tid < TROWS && s0 + tid < NS) {
        const float tot = dotb[tid][0] + dotb[tid][1] + dotb[tid][2] + dotb[tid][3] + linb[0];
        pred[b * NS + s0 + tid] = fmaxf(0.f, tot);
    }
}

// Length-regulator gather: one wave = 8 frames. 8 uniform idx loads, 8
// independent 1KB row loads in flight, 8 nontemporal 1KB stores (output is
// written once, never re-read -> bypass L2). Uses clang vector f32x4 (the
// nontemporal builtin rejects HIP_vector_type float4). No LDS, ~48 VGPR.
__global__ __launch_bounds__(256, 4) void gather8(const f32x4* __restrict__ x4,
                                                  const int* __restrict__ idx,
                                                  f32x4* __restrict__ out4, int L)
{
    const int g    = blockIdx.x;
    const int b    = g & 31;                       // batch b's chunks stay on XCD b%8
    const int f0   = (g >> 5) * (4 * FPW) + ((int)threadIdx.x >> 6) * FPW;
    const int lane = threadIdx.x & 63;
    const int* ib  = idx + (size_t)b * L;
    int pos[FPW];
#pragma unroll
    for (int j = 0; j < FPW; ++j)
        pos[j] = (f0 + j < L) ? ib[f0 + j] : -2;
    f32x4 v[FPW];
#pragma unroll
    for (int j = 0; j < FPW; ++j) {
        v[j] = (f32x4){0.f, 0.f, 0.f, 0.f};
        if (pos[j] >= 0) v[j] = x4[(((size_t)(b * NS + pos[j])) << 6) + lane];
    }
#pragma unroll
    for (int j = 0; j < FPW; ++j)
        if (pos[j] != -2)
            __builtin_nontemporal_store(v[j], &out4[(((size_t)b * L + f0 + j) << 6) + lane]);
}

extern "C" void kernel_launch(void* const* d_in, const int* in_sizes, int n_in,
                              void* d_out, int out_size, void* d_ws, size_t ws_size,
                              hipStream_t stream)
{
    const float* x    = (const float*)d_in[0];
    const float* targ = (const float*)d_in[1];
    const float* c1w  = (const float*)d_in[2];
    const float* c1b  = (const float*)d_in[3];
    const float* c2w  = (const float*)d_in[4];
    const float* c2b  = (const float*)d_in[5];
    const float* n1g  = (const float*)d_in[6];
    const float* n1b  = (const float*)d_in[7];
    const float* n2g  = (const float*)d_in[8];
    const float* n2b  = (const float*)d_in[9];
    const float* lw   = (const float*)d_in[10];
    const float* lb   = (const float*)d_in[11];

    const int L = (out_size - NB * NS) / (NB * NC);

    unsigned short* Bp1 = (unsigned short*)d_ws;          // 196608 bf16
    unsigned short* Bp2 = Bp1 + 196608;                   // 196608 bf16
    int* idx = (int*)(Bp2 + 196608);                      // [B,L]
    float* out  = (float*)d_out;                          // [B,L,256]
    float* pred = out + (size_t)NB * (size_t)L * NC;      // [B,S]

    prep_and_scan<<<dim3(512 + NB), 256, 0, stream>>>(c1w, c2w, Bp1, Bp2, targ, idx, L);

    conv_fused<<<dim3(CONV_BLOCKS), 256, 0, stream>>>(
        x, (const uint4*)Bp1, (const uint4*)Bp2,
        c1b, n1g, n1b, c2b, n2g, n2b, lw, lb, pred);

    const int nfb = (L + 4 * FPW - 1) / (4 * FPW);
    gather8<<<dim3(NB * nfb), 256, 0, stream>>>(
        (const f32x4*)x, idx, (f32x4*)out, L);
}

// Round 11
// 149.649 us; speedup vs baseline: 1.1501x; 1.1501x over previous
//
#include <hip/hip_runtime.h>
#include <hip/hip_bf16.h>

#define NB 32
#define NS 512
#define NC 256
#define NKSTEP 24      // K=768 im2col / 32
#define TROWS 30       // useful output rows per conv block
#define NT 18          // tiles per batch: 18*30 = 540 >= 512
#define HROWS 32       // h rows per block (s0-1 .. s0+30)
#define XROWS 34       // x rows staged  (s0-2 .. s0+31)
#define CONV_BLOCKS (NB * NT)   // 576
#define FPW 8          // frames per wave in gather path

typedef __attribute__((ext_vector_type(8))) short short8;
typedef __attribute__((ext_vector_type(4))) float f32x4;

__device__ __forceinline__ unsigned pack2(float a, float b) {
    __hip_bfloat16 ha = __float2bfloat16(a), hb = __float2bfloat16(b);
    return ((unsigned)(*(unsigned short*)&hb) << 16) | (unsigned)(*(unsigned short*)&ha);
}

// blocks 0..511: repack weights w[f][d][k] -> Bp[kstep][f][kgroup][8] bf16
// blocks 512..543: per-batch cumsum of rint(target) + scatter frame->row map
__global__ __launch_bounds__(256) void prep_and_scan(
    const float* __restrict__ w1, const float* __restrict__ w2,
    unsigned short* __restrict__ Bp1, unsigned short* __restrict__ Bp2,
    const float* __restrict__ target, int* __restrict__ idx, int L)
{
    __shared__ int bufa[512], bufb[512];
    const int t = threadIdx.x;

    if (blockIdx.x < 512) {
        const bool second = blockIdx.x >= 256;
        const int f = blockIdx.x & 255;
        const float* w = second ? w2 : w1;
        unsigned short* Bp = second ? Bp2 : Bp1;
        const float* wf = w + (size_t)f * 768 + t * 3;
        const float v[3] = {wf[0], wf[1], wf[2]};
#pragma unroll
        for (int shift = 0; shift < 3; ++shift) {
            const int k = shift * 256 + t;
            const int o = f * 32 + (k >> 5) * 8192 + (k & 31);
            __hip_bfloat16 h = __float2bfloat16(v[shift]);
            Bp[o] = *(unsigned short*)&h;
        }
        return;
    }

    const int b = blockIdx.x - 512;
    const float* tb = target + (size_t)b * NS;
    const int d0 = (int)rintf(tb[t]);
    const int d1 = (int)rintf(tb[t + 256]);
    bufa[t] = d0; bufa[t + 256] = d1;
    __syncthreads();
    int* src = bufa;
    int* dst = bufb;
    for (int off = 1; off < 512; off <<= 1) {
        for (int i = t; i < 512; i += 256) {
            int v = src[i];
            if (i >= off) v += src[i - off];
            dst[i] = v;
        }
        __syncthreads();
        int* tmp = src; src = dst; dst = tmp;
    }
    const int e0 = src[t], e1 = src[t + 256], total = src[511];
    int* ib = idx + (size_t)b * L;
    const int hi0 = e0 < L ? e0 : L;
    const int hi1 = e1 < L ? e1 : L;
    for (int k = e0 - d0; k < hi0; ++k) ib[k] = t;
    for (int k = e1 - d1; k < hi1; ++k) ib[k] = t + 256;
    for (int k = total + t; k < L; k += 256) ib[k] = -1;
}

// blocks < CONV_BLOCKS: fused duration predictor (conv1+LN+ReLU -> LDS alias,
//   conv2+LN+ReLU -> dot(lin_w)+ReLU -> pred). B prefetch ring DEPTH 4 (~3
//   ksteps ≈ 150-250cyc in flight, covers L2 latency).
// blocks >= CONV_BLOCKS: gather, one wave = 8 frames, nontemporal stores.
// launch_bounds(256,3): conv occupancy is grid-limited (576 blocks = 2.25/CU),
// so the 170-VGPR cap is free and stops the compiler from sinking the
// prefetch loads to shrink live ranges (round 10: VGPR=64 < 80 live = sunk).
__global__ __launch_bounds__(256, 3) void fused_conv_gather(
    const float* __restrict__ x,
    const uint4* __restrict__ Bp1, const uint4* __restrict__ Bp2,
    const float* __restrict__ bias1, const float* __restrict__ g1, const float* __restrict__ be1,
    const float* __restrict__ bias2, const float* __restrict__ g2, const float* __restrict__ be2,
    const float* __restrict__ linw, const float* __restrict__ linb,
    const int* __restrict__ idx, float* __restrict__ pred,
    const f32x4* __restrict__ x4, f32x4* __restrict__ out4, int L)
{
    __shared__ __align__(16) uint4 xs[XROWS * 32];   // 34 x 256 bf16, swizzled (17408B)
    __shared__ float red[HROWS][4][2];
    __shared__ float dotb[HROWS][4];
    unsigned short* hs = (unsigned short*)xs;        // h-tile alias (32 x 256 bf16)

    const int tid = threadIdx.x;

    if (blockIdx.x >= CONV_BLOCKS) {
        // ---------------- gather path ----------------
        const int g    = blockIdx.x - CONV_BLOCKS;
        const int b    = g & 31;                       // batch b's chunks stay on XCD b%8
        const int f0   = (g >> 5) * (4 * FPW) + (tid >> 6) * FPW;
        const int lane = tid & 63;
        const int* ib  = idx + (size_t)b * L;
        int pos[FPW];
#pragma unroll
        for (int j = 0; j < FPW; ++j)
            pos[j] = (f0 + j < L) ? ib[f0 + j] : -2;
        f32x4 v[FPW];
#pragma unroll
        for (int j = 0; j < FPW; ++j) {
            v[j] = (f32x4){0.f, 0.f, 0.f, 0.f};
            if (pos[j] >= 0) v[j] = x4[(((size_t)(b * NS + pos[j])) << 6) + lane];
        }
#pragma unroll
        for (int j = 0; j < FPW; ++j)
            if (pos[j] != -2)
                __builtin_nontemporal_store(v[j], &out4[(((size_t)b * L + f0 + j) << 6) + lane]);
        return;
    }

    // ---------------- fused conv path ----------------
    const int b  = blockIdx.x / NT;
    const int t  = blockIdx.x - b * NT;
    const int s0 = t * TROWS;

    // stage x rows s0-2 .. s0+31 as bf16, swizzled (slot ^= (row&7)<<2)
    {
        const int slot = tid & 31;
        for (int r = tid >> 5; r < XROWS; r += 8) {
            const int s = s0 - 2 + r;
            uint4 v = {0u, 0u, 0u, 0u};
            if (s >= 0 && s < NS) {
                const float* src = x + ((size_t)(b * NS + s)) * NC + slot * 8;
                const float4 lo = *(const float4*)src;
                const float4 hi = *(const float4*)(src + 4);
                v.x = pack2(lo.x, lo.y); v.y = pack2(lo.z, lo.w);
                v.z = pack2(hi.x, hi.y); v.w = pack2(hi.z, hi.w);
            }
            xs[r * 32 + (slot ^ ((r & 7) << 2))] = v;
        }
    }
    __syncthreads();

    const int lane = tid & 63;
    const int w    = tid >> 6;
    const int n0   = w << 6;
    const int l15  = lane & 15;
    const int lg   = lane >> 4;

    auto ldax = [&](int ks, int mi) -> short8 {
        const int row = mi * 16 + l15 + (ks >> 3);
        int slot = ((ks & 7) << 2) + lg;
        slot ^= (row & 7) << 2;
        return *(const short8*)&xs[row * 32 + slot];
    };
    auto ldah = [&](int ks, int mi) -> short8 {
        const int row = mi * 16 + l15 + (ks >> 3);
        int slot = ((ks & 7) << 2) + lg;
        slot ^= (row & 7) << 2;
        return *(const short8*)&hs[row * 256 + slot * 8];
    };

    const uint4* bb1 = Bp1 + (size_t)(n0 + l15) * 4 + lg;
    const uint4* bb2 = Bp2 + (size_t)(n0 + l15) * 4 + lg;

    f32x4 acc[2][4];
    short8 areg[2][2], breg[4][4];

    // ======== conv1: h rows 0..31 (seq s0-1 .. s0+30) ========
#pragma unroll
    for (int mi = 0; mi < 2; ++mi)
#pragma unroll
        for (int ni = 0; ni < 4; ++ni) acc[mi][ni] = (f32x4){0.f, 0.f, 0.f, 0.f};
#pragma unroll
    for (int q = 0; q < 4; ++q)
#pragma unroll
        for (int ni = 0; ni < 4; ++ni) breg[q][ni] = *(const short8*)(const void*)(bb1 + q * 1024 + ni * 64);
#pragma unroll
    for (int q = 0; q < 2; ++q)
#pragma unroll
        for (int mi = 0; mi < 2; ++mi) areg[q][mi] = ldax(q, mi);

#pragma unroll
    for (int p = 0; p < NKSTEP; ++p) {
        const int bs = p & 3, as = p & 1;
#pragma unroll
        for (int mi = 0; mi < 2; ++mi)
#pragma unroll
            for (int ni = 0; ni < 4; ++ni)
                acc[mi][ni] = __builtin_amdgcn_mfma_f32_16x16x32_bf16(
                    areg[as][mi], breg[bs][ni], acc[mi][ni], 0, 0, 0);
        if (p + 4 < NKSTEP) {
#pragma unroll
            for (int ni = 0; ni < 4; ++ni) breg[bs][ni] = *(const short8*)(const void*)(bb1 + (p + 4) * 1024 + ni * 64);
        }
        if (p + 2 < NKSTEP) {
#pragma unroll
            for (int mi = 0; mi < 2; ++mi) areg[as][mi] = ldax(p + 2, mi);
        }
    }

    // LN1 stats
    {
        float bv[4];
#pragma unroll
        for (int ni = 0; ni < 4; ++ni) bv[ni] = bias1[n0 + ni * 16 + l15];
#pragma unroll
        for (int mi = 0; mi < 2; ++mi) {
            float s[4] = {0, 0, 0, 0}, q[4] = {0, 0, 0, 0};
#pragma unroll
            for (int ni = 0; ni < 4; ++ni)
#pragma unroll
                for (int i = 0; i < 4; ++i) {
                    const float v = (acc[mi][ni][i] += bv[ni]);
                    s[i] += v; q[i] += v * v;
                }
#pragma unroll
            for (int i = 0; i < 4; ++i)
#pragma unroll
                for (int m = 1; m < 16; m <<= 1) {
                    s[i] += __shfl_xor(s[i], m, 64);
                    q[i] += __shfl_xor(q[i], m, 64);
                }
            if (l15 == 0) {
#pragma unroll
                for (int i = 0; i < 4; ++i) {
                    red[mi * 16 + lg * 4 + i][w][0] = s[i];
                    red[mi * 16 + lg * 4 + i][w][1] = q[i];
                }
            }
        }
    }
    __syncthreads();   // all xs reads done -> hs may overwrite xs

    // LN1 apply + ReLU + zero seq-pad rows -> hs (swizzled bf16, aliases xs)
    {
        float gv[4], bt[4];
#pragma unroll
        for (int ni = 0; ni < 4; ++ni) { gv[ni] = g1[n0 + ni * 16 + l15]; bt[ni] = be1[n0 + ni * 16 + l15]; }
#pragma unroll
        for (int mi = 0; mi < 2; ++mi)
#pragma unroll
            for (int i = 0; i < 4; ++i) {
                const int row = mi * 16 + lg * 4 + i;
                const int sh  = s0 - 1 + row;
                const bool ok = (sh >= 0) && (sh < NS);
                float sum = 0.f, sq = 0.f;
#pragma unroll
                for (int ww = 0; ww < 4; ++ww) { sum += red[row][ww][0]; sq += red[row][ww][1]; }
                const float mu = sum * (1.f / 256.f);
                const float rs = rsqrtf(sq * (1.f / 256.f) - mu * mu + 1e-5f);
#pragma unroll
                for (int ni = 0; ni < 4; ++ni) {
                    const int col = n0 + ni * 16 + l15;
                    float y = fmaxf(0.f, (acc[mi][ni][i] - mu) * rs * gv[ni] + bt[ni]);
                    if (!ok) y = 0.f;
                    __hip_bfloat16 hv = __float2bfloat16(y);
                    const int slot = (col >> 3) ^ ((row & 7) << 2);
                    hs[row * 256 + slot * 8 + (col & 7)] = *(unsigned short*)&hv;
                }
            }
    }
    __syncthreads();

    // ======== conv2: out rows 0..31, rows >= TROWS discarded ========
#pragma unroll
    for (int mi = 0; mi < 2; ++mi)
#pragma unroll
        for (int ni = 0; ni < 4; ++ni) acc[mi][ni] = (f32x4){0.f, 0.f, 0.f, 0.f};
#pragma unroll
    for (int q = 0; q < 4; ++q)
#pragma unroll
        for (int ni = 0; ni < 4; ++ni) breg[q][ni] = *(const short8*)(const void*)(bb2 + q * 1024 + ni * 64);
#pragma unroll
    for (int q = 0; q < 2; ++q)
#pragma unroll
        for (int mi = 0; mi < 2; ++mi) areg[q][mi] = ldah(q, mi);

#pragma unroll
    for (int p = 0; p < NKSTEP; ++p) {
        const int bs = p & 3, as = p & 1;
#pragma unroll
        for (int mi = 0; mi < 2; ++mi)
#pragma unroll
            for (int ni = 0; ni < 4; ++ni)
                acc[mi][ni] = __builtin_amdgcn_mfma_f32_16x16x32_bf16(
                    areg[as][mi], breg[bs][ni], acc[mi][ni], 0, 0, 0);
        if (p + 4 < NKSTEP) {
#pragma unroll
            for (int ni = 0; ni < 4; ++ni) breg[bs][ni] = *(const short8*)(const void*)(bb2 + (p + 4) * 1024 + ni * 64);
        }
        if (p + 2 < NKSTEP) {
#pragma unroll
            for (int mi = 0; mi < 2; ++mi) areg[as][mi] = ldah(p + 2, mi);
        }
    }

    // LN2 stats
    {
        float bv[4];
#pragma unroll
        for (int ni = 0; ni < 4; ++ni) bv[ni] = bias2[n0 + ni * 16 + l15];
#pragma unroll
        for (int mi = 0; mi < 2; ++mi) {
            float s[4] = {0, 0, 0, 0}, q[4] = {0, 0, 0, 0};
#pragma unroll
            for (int ni = 0; ni < 4; ++ni)
#pragma unroll
                for (int i = 0; i < 4; ++i) {
                    const float v = (acc[mi][ni][i] += bv[ni]);
                    s[i] += v; q[i] += v * v;
                }
#pragma unroll
            for (int i = 0; i < 4; ++i)
#pragma unroll
                for (int m = 1; m < 16; m <<= 1) {
                    s[i] += __shfl_xor(s[i], m, 64);
                    q[i] += __shfl_xor(q[i], m, 64);
                }
            if (l15 == 0) {
#pragma unroll
                for (int i = 0; i < 4; ++i) {
                    red[mi * 16 + lg * 4 + i][w][0] = s[i];
                    red[mi * 16 + lg * 4 + i][w][1] = q[i];
                }
            }
        }
    }
    __syncthreads();

    // LN2 apply + ReLU + dot(lin_w) partials
    {
        float gv[4], bt[4], lwv[4];
#pragma unroll
        for (int ni = 0; ni < 4; ++ni) {
            const int col = n0 + ni * 16 + l15;
            gv[ni] = g2[col]; bt[ni] = be2[col]; lwv[ni] = linw[col];
        }
#pragma unroll
        for (int mi = 0; mi < 2; ++mi)
#pragma unroll
            for (int i = 0; i < 4; ++i) {
                const int row = mi * 16 + lg * 4 + i;
                float sum = 0.f, sq = 0.f;
#pragma unroll
                for (int ww = 0; ww < 4; ++ww) { sum += red[row][ww][0]; sq += red[row][ww][1]; }
                const float mu = sum * (1.f / 256.f);
                const float rs = rsqrtf(sq * (1.f / 256.f) - mu * mu + 1e-5f);
                float p = 0.f;
#pragma unroll
                for (int ni = 0; ni < 4; ++ni)
                    p += fmaxf(0.f, (acc[mi][ni][i] - mu) * rs * gv[ni] + bt[ni]) * lwv[ni];
#pragma unroll
                for (int m = 1; m < 16; m <<= 1) p += __shfl_xor(p, m, 64);
                if (l15 == 0) dotb[row][w] = p;
            }
    }
    __syncthreads();

    if (tid < TROWS && s0 + tid < NS) {
        const float tot = dotb[tid][0] + dotb[tid][1] + dotb[tid][2] + dotb[tid][3] + linb[0];
        pred[b * NS + s0 + tid] = fmaxf(0.f, tot);
    }
}

extern "C" void kernel_launch(void* const* d_in, const int* in_sizes, int n_in,
                              void* d_out, int out_size, void* d_ws, size_t ws_size,
                              hipStream_t stream)
{
    const float* x    = (const float*)d_in[0];
    const float* targ = (const float*)d_in[1];
    const float* c1w  = (const float*)d_in[2];
    const float* c1b  = (const float*)d_in[3];
    const float* c2w  = (const float*)d_in[4];
    const float* c2b  = (const float*)d_in[5];
    const float* n1g  = (const float*)d_in[6];
    const float* n1b  = (const float*)d_in[7];
    const float* n2g  = (const float*)d_in[8];
    const float* n2b  = (const float*)d_in[9];
    const float* lw   = (const float*)d_in[10];
    const float* lb   = (const float*)d_in[11];

    const int L = (out_size - NB * NS) / (NB * NC);

    unsigned short* Bp1 = (unsigned short*)d_ws;          // 196608 bf16
    unsigned short* Bp2 = Bp1 + 196608;                   // 196608 bf16
    int* idx = (int*)(Bp2 + 196608);                      // [B,L]
    float* out  = (float*)d_out;                          // [B,L,256]
    float* pred = out + (size_t)NB * (size_t)L * NC;      // [B,S]

    prep_and_scan<<<dim3(512 + NB), 256, 0, stream>>>(c1w, c2w, Bp1, Bp2, targ, idx, L);

    const int nfb = (L + 4 * FPW - 1) / (4 * FPW);
    fused_conv_gather<<<dim3(CONV_BLOCKS + NB * nfb), 256, 0, stream>>>(
        x, (const uint4*)Bp1, (const uint4*)Bp2,
        c1b, n1g, n1b, c2b, n2g, n2b, lw, lb,
        idx, pred, (const f32x4*)x, (f32x4*)out, L);
}